// Round 24
// baseline (3442.440 us; speedup 1.0000x reference)
//
#include <hip/hip_runtime.h>
#include <math.h>

#define BATCH 4096
#define NIN   4096
#define NOUT  4096
// R9-verified ACID ORDER (frozen): [512x8] k-panels, single ascending fmaf
// chain, fold every 512 k, f32 epilogue. BASE on MFMA pipe (R13/R19-verified).
// R24: B-signs read DIRECT FROM GLOBAL (per-lane, 16-lane-broadcast, L1-resident
// 8KB/stage slice) -> DS pipe carries A only (2 b128/k/wave, 24 cyc) and the
// VALU becomes the binder (128 cyc/k). Ledger: R20=2001 R21=2085(bf16 signs)
// R22=2071(barrier-free) R23=2002(setprio) -> DS/VALU balance was the wall;
// this re-routes bytes onto the idle VMEM pipe instead of shrinking them.

typedef __attribute__((ext_vector_type(8))) short bf16x8;
typedef __attribute__((ext_vector_type(8))) unsigned short u16x8;
typedef __attribute__((ext_vector_type(4))) float f32x4;

__device__ __forceinline__ float2 compute_terms(float xv) {
    float h  = (float)exp10(-(double)xv);
    float oh = 1e-14f / h;
    return make_float2(h * 0.1f, oh * 0.1f);
}
__device__ __forceinline__ unsigned short bf16_rne(float v) {
    unsigned int b = __float_as_uint(v);
    return (unsigned short)((b + 0x7FFFu + ((b >> 16) & 1u)) >> 16);
}
__device__ __forceinline__ float signf_of(float wv) {
    return (wv > 0.f) ? 1.f : ((wv < 0.f) ? -1.f : 0.f);
}
__device__ __forceinline__ unsigned short signbf16_of(float wv) {
    return (wv > 0.f) ? 0x3F80u : ((wv < 0.f) ? 0xBF80u : 0u);
}

#define GLOAD16(g, l)                                                        \
    __builtin_amdgcn_global_load_lds(                                        \
        (const __attribute__((address_space(1))) void*)(g),                  \
        (__attribute__((address_space(3))) void*)(l), 16, 0, 0)

// --- merged precompute: blocks y<64 process x -> AaT[k][m] f32 + Ab[m][k] bf16;
//     blocks y>=64 process w -> signT[n][k] bf16 + signF[k][n] f32 ---
__global__ __launch_bounds__(256) void precompute_all(const float* __restrict__ x,
                                                      const float* __restrict__ w,
                                                      float* __restrict__ aaT,
                                                      unsigned short* __restrict__ ab,
                                                      unsigned short* __restrict__ sT,
                                                      float* __restrict__ sF) {
    const int tid = threadIdx.x;
    if (blockIdx.y < 64) {
        __shared__ float tile[64][65];
        const int m0 = blockIdx.y * 64, k0 = blockIdx.x * 64;
        #pragma unroll
        for (int it = 0; it < 4; ++it) {
            int idx = tid + it * 256;
            int row = idx >> 4, q = idx & 15;
            float4 xv = *(const float4*)(x + (size_t)(m0 + row) * NIN + k0 + q * 4);
            float2 t0 = compute_terms(xv.x), t1 = compute_terms(xv.y),
                   t2 = compute_terms(xv.z), t3 = compute_terms(xv.w);
            *(ushort4*)(ab + (size_t)(m0 + row) * NIN + k0 + q * 4) =
                make_ushort4(bf16_rne(t0.y), bf16_rne(t1.y), bf16_rne(t2.y), bf16_rne(t3.y));
            tile[row][q * 4 + 0] = t0.x; tile[row][q * 4 + 1] = t1.x;
            tile[row][q * 4 + 2] = t2.x; tile[row][q * 4 + 3] = t3.x;
        }
        __syncthreads();
        #pragma unroll
        for (int it = 0; it < 4; ++it) {
            int idx = tid + it * 256;
            int krow = idx >> 4, q = idx & 15;
            float4 v = make_float4(tile[q * 4 + 0][krow], tile[q * 4 + 1][krow],
                                   tile[q * 4 + 2][krow], tile[q * 4 + 3][krow]);
            *(float4*)(aaT + (size_t)(k0 + krow) * NIN + m0 + q * 4) = v;
        }
    } else {
        __shared__ unsigned short tileu[64][68];
        const int k0 = (blockIdx.y - 64) * 64, n0 = blockIdx.x * 64;
        #pragma unroll
        for (int it = 0; it < 4; ++it) {
            int idx = tid + it * 256;
            int krow = idx >> 4, q = idx & 15;
            float4 wv = *(const float4*)(w + (size_t)(k0 + krow) * NOUT + n0 + q * 4);
            *(ushort4*)&tileu[krow][q * 4] =
                make_ushort4(signbf16_of(wv.x), signbf16_of(wv.y), signbf16_of(wv.z), signbf16_of(wv.w));
            *(float4*)(sF + (size_t)(k0 + krow) * NOUT + n0 + q * 4) =
                make_float4(signf_of(wv.x), signf_of(wv.y), signf_of(wv.z), signf_of(wv.w));
        }
        __syncthreads();
        #pragma unroll
        for (int it = 0; it < 2; ++it) {
            int idx = tid + it * 256;
            int n = idx >> 3, kc = idx & 7;
            u16x8 v;
            #pragma unroll
            for (int j = 0; j < 8; ++j) v[j] = tileu[kc * 8 + j][n];
            *(u16x8*)(sT + (size_t)(n0 + n) * NIN + k0 + kc * 8) = v;
        }
    }
}

// --- fused kernel: acid VALU main loop + base MFMA tail ---
// LDS: As[2][16][128] f32 = 16384 B (A only; B-signs direct from global),
// aliased by BoutH[128][68] f32 = 34816 B in the tail -> block LDS = 34816.
__global__ __launch_bounds__(256, 3) void acid_base_fused(const float* __restrict__ AaT,
                                                          const float* __restrict__ SignF,
                                                          const unsigned short* __restrict__ Ab,
                                                          const unsigned short* __restrict__ SignT,
                                                          float* __restrict__ out) {
    __shared__ __align__(16) char smem[34816];
    float (*As)[16][128] = (float (*)[16][128])smem;   // [2][16][128]
    float (*BoutH)[68]   = (float (*)[68])smem;        // [128][68] tail alias

    const int tid = threadIdx.x;
    const int tx  = tid & 15;      // cols tx*4..+3 and 64+tx*4..+3
    const int ty  = tid >> 4;      // rows ty*8..+7
    const int w   = tid >> 6;      // wave
    const int l   = tid & 63;
    const int g   = l >> 4;        // MFMA k-group
    const int r16 = l & 15;
    const int bm0 = blockIdx.y * 128;
    const int bn0 = blockIdx.x * 128;

    const int lrow = (l >> 5);       // sub-row within a 1024B glds
    const int lcol = (l & 31) * 4;   // f32 col within 128-wide row

    // per-thread sign row pointers (16-lane-identical -> TA broadcast, L1-resident)
    const float* sf0 = SignF + bn0 + tx * 4;
    const float* sf1 = SignF + bn0 + 64 + tx * 4;

    float ma[8][8] = {}, ca[8][8] = {};

    #define AISSUE(s, b)                                                            \
        {                                                                           \
            const int k0_ = (s) * 16;                                               \
            _Pragma("unroll")                                                       \
            for (int j = 0; j < 2; ++j) {                                           \
                const int kr_ = w * 4 + 2 * j;                                      \
                GLOAD16(AaT + (size_t)(k0_ + kr_ + lrow) * NIN + bm0 + lcol,        \
                        &As[b][kr_][0]);                                            \
            }                                                                       \
        }

    // 16 ascending k; fold every 32 stages (= 512 k, R9-frozen schedule).
    // sn from GLOBAL (same f32 +-1/0 values as the old LDS copy -> bit-identical).
    #define ACOMP(s, b)                                                             \
        {                                                                           \
            _Pragma("unroll 4")                                                     \
            for (int k = 0; k < 16; ++k) {                                          \
                const size_t krow_ = (size_t)((s) * 16 + k) * NOUT;                 \
                const float4 pa = *(const float4*)&As[b][k][ty * 8];                \
                const float4 pb = *(const float4*)&As[b][k][ty * 8 + 4];            \
                const float4 s0 = *(const float4*)(sf0 + krow_);                    \
                const float4 s1 = *(const float4*)(sf1 + krow_);                    \
                const float av[8] = {pa.x, pa.y, pa.z, pa.w, pb.x, pb.y, pb.z, pb.w};\
                const float sn[8] = {s0.x, s0.y, s0.z, s0.w, s1.x, s1.y, s1.z, s1.w};\
                _Pragma("unroll")                                                   \
                for (int m = 0; m < 8; ++m)                                         \
                    _Pragma("unroll")                                               \
                    for (int n = 0; n < 8; ++n)                                     \
                        ca[m][n] = fmaf(av[m], sn[n], ca[m][n]);                    \
            }                                                                       \
            if ((((s) + 1) & 31) == 0) {                                            \
                _Pragma("unroll")                                                   \
                for (int m = 0; m < 8; ++m)                                         \
                    _Pragma("unroll")                                               \
                    for (int n = 0; n < 8; ++n) {                                   \
                        ma[m][n] += ca[m][n]; ca[m][n] = 0.f;                       \
                    }                                                               \
            }                                                                       \
        }

    AISSUE(0, 0);
    __syncthreads();   // buf0 ready

    for (int s2 = 0; s2 < 128; ++s2) {
        const int s = 2 * s2;
        AISSUE(s + 1, 1);
        ACOMP(s, 0);
        __syncthreads();
        if (s + 2 < 256) AISSUE(s + 2, 0);
        ACOMP(s + 1, 1);
        __syncthreads();
    }

    // ---- base MFMA tail (R19/R20-verified): acc reuses ca's dead budget ----
    f32x4 acc[2][8] = {};
    {
        const unsigned short* a0 = Ab + (size_t)(bm0 + w * 32 + r16) * NIN + g * 8;
        const unsigned short* a1 = Ab + (size_t)(bm0 + w * 32 + 16 + r16) * NIN + g * 8;
        #pragma unroll 4
        for (int s = 0; s < 128; ++s) {
            const int k0 = s * 32;
            bf16x8 af0 = *(const bf16x8*)(a0 + k0);
            bf16x8 af1 = *(const bf16x8*)(a1 + k0);
            #pragma unroll
            for (int tc = 0; tc < 8; ++tc) {
                bf16x8 bf = *(const bf16x8*)(SignT + (size_t)(bn0 + tc * 16 + r16) * NIN + k0 + g * 8);
                acc[0][tc] = __builtin_amdgcn_mfma_f32_16x16x32_bf16(af0, bf, acc[0][tc], 0, 0, 0);
                acc[1][tc] = __builtin_amdgcn_mfma_f32_16x16x32_bf16(af1, bf, acc[1][tc], 0, 0, 0);
            }
        }
    }

    // ---- combine + epilogue, two column halves (R18/R19-verified) ----
    __syncthreads();   // As dead; BoutH alias safe
    #pragma unroll
    for (int hh = 0; hh < 2; ++hh) {
        #pragma unroll
        for (int tr = 0; tr < 2; ++tr)
            #pragma unroll
            for (int tc = 0; tc < 4; ++tc)
                #pragma unroll
                for (int rr = 0; rr < 4; ++rr)
                    BoutH[w * 32 + tr * 16 + g * 4 + rr][tc * 16 + r16] = acc[tr][hh * 4 + tc][rr];
        __syncthreads();
        #pragma unroll
        for (int m = 0; m < 8; ++m) {
            const int row = ty * 8 + m;
            const float4 bv = *(const float4*)&BoutH[row][tx * 4];
            const float bb[4] = {bv.x, bv.y, bv.z, bv.w};
            float ph[4];
            #pragma unroll
            for (int n = 0; n < 4; ++n) {
                float r    = ma[m][hh * 4 + n] - bb[n];
                float conc = fabsf(r) / 409.6f;
                float hc   = (r < 0.f) ? (1e-14f / conc) : conc;
                ph[n]      = (-logf(hc)) / 2.302585092994046f;
            }
            *(float4*)(out + (size_t)(bm0 + row) * NOUT + bn0 + hh * 64 + tx * 4) =
                make_float4(ph[0], ph[1], ph[2], ph[3]);
        }
        __syncthreads();
    }
    #undef AISSUE
    #undef ACOMP
}

// Fallback (ws too small): R9's proven all-VALU kernel, on-the-fly terms.
__global__ __launch_bounds__(256, 2) void acid_gemm_fly(const float* __restrict__ X,
                                                        const float* __restrict__ W,
                                                        float* __restrict__ out) {
    __shared__ float2 Asf[32][128 + 2];
    __shared__ float  Bsf[32][64];
    const int tid = threadIdx.x;
    const int tx = tid & 15, ty = tid >> 4;
    const int bm0 = blockIdx.y * 128, bn0 = blockIdx.x * 64;
    float ma[8][4] = {}, mb[8][4] = {}, ca[8][4] = {}, cb[8][4] = {};
    for (int s = 0; s < 128; ++s) {
        const int k0 = s * 32;
        for (int idx = tid; idx < 128 * 32; idx += 256) {
            int m = idx >> 5, k = idx & 31;
            Asf[k][m] = compute_terms(X[(size_t)(bm0 + m) * NIN + k0 + k]);
        }
        for (int idx = tid; idx < 32 * 64; idx += 256) {
            int k = idx >> 6, c = idx & 63;
            Bsf[k][c] = signf_of(W[(size_t)(k0 + k) * NOUT + bn0 + c]);
        }
        __syncthreads();
        #pragma unroll 4
        for (int k = 0; k < 32; ++k) {
            float2 av[8]; float sv[4];
            #pragma unroll
            for (int m = 0; m < 8; ++m) av[m] = Asf[k][ty * 8 + m];
            #pragma unroll
            for (int n = 0; n < 4; ++n) sv[n] = Bsf[k][tx * 4 + n];
            #pragma unroll
            for (int m = 0; m < 8; ++m)
                #pragma unroll
                for (int n = 0; n < 4; ++n) {
                    ca[m][n] = fmaf(av[m].x, sv[n], ca[m][n]);
                    cb[m][n] = fmaf(av[m].y, sv[n], cb[m][n]);
                }
        }
        if (((s + 1) & 15) == 0) {
            #pragma unroll
            for (int m = 0; m < 8; ++m)
                #pragma unroll
                for (int n = 0; n < 4; ++n) {
                    ma[m][n] += ca[m][n]; ca[m][n] = 0.f;
                    mb[m][n] += cb[m][n]; cb[m][n] = 0.f;
                }
        }
        __syncthreads();
    }
    #pragma unroll
    for (int m = 0; m < 8; ++m) {
        int row = bm0 + ty * 8 + m;
        #pragma unroll
        for (int n = 0; n < 4; ++n) {
            int col = bn0 + tx * 4 + n;
            float r = ma[m][n] - mb[m][n];
            float conc = fabsf(r) / 409.6f;
            float hc = (r < 0.f) ? (1e-14f / conc) : conc;
            out[(size_t)row * NOUT + col] = (-logf(hc)) / 2.302585092994046f;
        }
    }
}

extern "C" void kernel_launch(void* const* d_in, const int* in_sizes, int n_in,
                              void* d_out, int out_size, void* d_ws, size_t ws_size,
                              hipStream_t stream) {
    const float* x = (const float*)d_in[0];
    const float* w = (const float*)d_in[1];
    float* out = (float*)d_out;

    const size_t nElem = (size_t)BATCH * NIN;
    // ws layout: AaT f32 | Ab u16 | signT u16 | signF f32  = 12 B/elem (201 MB)
    float*          aaT   = (float*)d_ws;
    unsigned short* ab    = (unsigned short*)((char*)d_ws + nElem * 4);
    unsigned short* signT = (unsigned short*)((char*)d_ws + nElem * 6);
    float*          signF = (float*)((char*)d_ws + nElem * 8);

    if (ws_size >= nElem * 12) {
        precompute_all <<<dim3(64, 128), 256, 0, stream>>>(x, w, aaT, ab, signT, signF);
        acid_base_fused<<<dim3(32, 32), 256, 0, stream>>>(aaT, signF, ab, signT, out);
    } else {
        acid_gemm_fly<<<dim3(NOUT / 64, BATCH / 128), dim3(256), 0, stream>>>(x, w, out);
    }
}

// Round 25
// 2001.222 us; speedup vs baseline: 1.7202x; 1.7202x over previous
//
#include <hip/hip_runtime.h>
#include <math.h>

#define BATCH 4096
#define NIN   4096
#define NOUT  4096
// R9-verified ACID ORDER (frozen): [512x8] k-panels, single ascending fmaf
// chain, fold every 512 k, f32 epilogue. BASE on MFMA pipe (R13/R19-verified).
// R25 = R20/R23 staging (LDS f32 signs; R24's global-B reads REJECTED, -70%)
// + v_pk_fma_f32 acid inner loop: n-dim packed pairwise, B pairs free from
// float4 reads, per-component IEEE == scalar fmaf -> bit-exact. Halves VALU
// instruction count; dual-pipe pk would halve VALU execution.

typedef __attribute__((ext_vector_type(8))) short bf16x8;
typedef __attribute__((ext_vector_type(8))) unsigned short u16x8;
typedef __attribute__((ext_vector_type(4))) float f32x4;
typedef __attribute__((ext_vector_type(2))) float f32x2;

__device__ __forceinline__ float2 compute_terms(float xv) {
    float h  = (float)exp10(-(double)xv);
    float oh = 1e-14f / h;
    return make_float2(h * 0.1f, oh * 0.1f);
}
__device__ __forceinline__ unsigned short bf16_rne(float v) {
    unsigned int b = __float_as_uint(v);
    return (unsigned short)((b + 0x7FFFu + ((b >> 16) & 1u)) >> 16);
}
__device__ __forceinline__ float signf_of(float wv) {
    return (wv > 0.f) ? 1.f : ((wv < 0.f) ? -1.f : 0.f);
}
__device__ __forceinline__ unsigned short signbf16_of(float wv) {
    return (wv > 0.f) ? 0x3F80u : ((wv < 0.f) ? 0xBF80u : 0u);
}

#define GLOAD16(g, l)                                                        \
    __builtin_amdgcn_global_load_lds(                                        \
        (const __attribute__((address_space(1))) void*)(g),                  \
        (__attribute__((address_space(3))) void*)(l), 16, 0, 0)

// --- merged precompute: blocks y<64 process x -> AaT[k][m] f32 + Ab[m][k] bf16;
//     blocks y>=64 process w -> signT[n][k] bf16 + signF[k][n] f32 ---
__global__ __launch_bounds__(256) void precompute_all(const float* __restrict__ x,
                                                      const float* __restrict__ w,
                                                      float* __restrict__ aaT,
                                                      unsigned short* __restrict__ ab,
                                                      unsigned short* __restrict__ sT,
                                                      float* __restrict__ sF) {
    const int tid = threadIdx.x;
    if (blockIdx.y < 64) {
        __shared__ float tile[64][65];
        const int m0 = blockIdx.y * 64, k0 = blockIdx.x * 64;
        #pragma unroll
        for (int it = 0; it < 4; ++it) {
            int idx = tid + it * 256;
            int row = idx >> 4, q = idx & 15;
            float4 xv = *(const float4*)(x + (size_t)(m0 + row) * NIN + k0 + q * 4);
            float2 t0 = compute_terms(xv.x), t1 = compute_terms(xv.y),
                   t2 = compute_terms(xv.z), t3 = compute_terms(xv.w);
            *(ushort4*)(ab + (size_t)(m0 + row) * NIN + k0 + q * 4) =
                make_ushort4(bf16_rne(t0.y), bf16_rne(t1.y), bf16_rne(t2.y), bf16_rne(t3.y));
            tile[row][q * 4 + 0] = t0.x; tile[row][q * 4 + 1] = t1.x;
            tile[row][q * 4 + 2] = t2.x; tile[row][q * 4 + 3] = t3.x;
        }
        __syncthreads();
        #pragma unroll
        for (int it = 0; it < 4; ++it) {
            int idx = tid + it * 256;
            int krow = idx >> 4, q = idx & 15;
            float4 v = make_float4(tile[q * 4 + 0][krow], tile[q * 4 + 1][krow],
                                   tile[q * 4 + 2][krow], tile[q * 4 + 3][krow]);
            *(float4*)(aaT + (size_t)(k0 + krow) * NIN + m0 + q * 4) = v;
        }
    } else {
        __shared__ unsigned short tileu[64][68];
        const int k0 = (blockIdx.y - 64) * 64, n0 = blockIdx.x * 64;
        #pragma unroll
        for (int it = 0; it < 4; ++it) {
            int idx = tid + it * 256;
            int krow = idx >> 4, q = idx & 15;
            float4 wv = *(const float4*)(w + (size_t)(k0 + krow) * NOUT + n0 + q * 4);
            *(ushort4*)&tileu[krow][q * 4] =
                make_ushort4(signbf16_of(wv.x), signbf16_of(wv.y), signbf16_of(wv.z), signbf16_of(wv.w));
            *(float4*)(sF + (size_t)(k0 + krow) * NOUT + n0 + q * 4) =
                make_float4(signf_of(wv.x), signf_of(wv.y), signf_of(wv.z), signf_of(wv.w));
        }
        __syncthreads();
        #pragma unroll
        for (int it = 0; it < 2; ++it) {
            int idx = tid + it * 256;
            int n = idx >> 3, kc = idx & 7;
            u16x8 v;
            #pragma unroll
            for (int j = 0; j < 8; ++j) v[j] = tileu[kc * 8 + j][n];
            *(u16x8*)(sT + (size_t)(n0 + n) * NIN + k0 + kc * 8) = v;
        }
    }
}

// --- fused kernel: acid pk-fma main loop + base MFMA tail ---
// LDS: As[2][16][128] + Bs[2][16][128] f32 = 32768 B, aliased by
// BoutH[128][68] f32 = 34816 B in the tail -> block LDS = 34816.
__global__ __launch_bounds__(256, 3) void acid_base_fused(const float* __restrict__ AaT,
                                                          const float* __restrict__ SignF,
                                                          const unsigned short* __restrict__ Ab,
                                                          const unsigned short* __restrict__ SignT,
                                                          float* __restrict__ out) {
    __shared__ __align__(16) char smem[34816];
    float (*As)[16][128] = (float (*)[16][128])smem;            // [2][16][128]
    float (*Bs)[16][128] = (float (*)[16][128])(smem + 16384);  // [2][16][128]
    float (*BoutH)[68]   = (float (*)[68])smem;                 // [128][68] tail alias

    const int tid = threadIdx.x;
    const int tx  = tid & 15;      // cols tx*4..+3 and 64+tx*4..+3
    const int ty  = tid >> 4;      // rows ty*8..+7
    const int w   = tid >> 6;      // wave
    const int l   = tid & 63;
    const int g   = l >> 4;        // MFMA k-group
    const int r16 = l & 15;
    const int bm0 = blockIdx.y * 128;
    const int bn0 = blockIdx.x * 128;

    const int lrow = (l >> 5);       // sub-row within a 1024B glds
    const int lcol = (l & 31) * 4;   // f32 col within 128-wide row

    // packed accumulators over n-pairs: [m][j], j=0..3 -> n={2j,2j+1} in the
    // order (tx*4+0, tx*4+1), (tx*4+2, tx*4+3), (64+tx*4+0, +1), (64+tx*4+2, +3)
    f32x2 ma2[8][4] = {}, ca2[8][4] = {};

    #define AISSUE(s, b)                                                            \
        {                                                                           \
            const int k0_ = (s) * 16;                                               \
            _Pragma("unroll")                                                       \
            for (int j = 0; j < 2; ++j) {                                           \
                const int kr_ = w * 4 + 2 * j;                                      \
                GLOAD16(AaT   + (size_t)(k0_ + kr_ + lrow) * NIN + bm0 + lcol,      \
                        &As[b][kr_][0]);                                            \
                GLOAD16(SignF + (size_t)(k0_ + kr_ + lrow) * NIN + bn0 + lcol,      \
                        &Bs[b][kr_][0]);                                            \
            }                                                                       \
        }

    // 16 ascending k; fold every 32 stages (= 512 k, R9-frozen schedule).
    // Packed v_pk_fma_f32 over n-pairs: per-component IEEE fma == scalar fmaf,
    // each (m,n) chain still one fma per k in ascending k -> bit-exact.
    #define ACOMP(s, b)                                                             \
        {                                                                           \
            _Pragma("unroll 4")                                                     \
            for (int k = 0; k < 16; ++k) {                                          \
                const float4 pa = *(const float4*)&As[b][k][ty * 8];                \
                const float4 pb = *(const float4*)&As[b][k][ty * 8 + 4];            \
                const f32x2 s01 = *(const f32x2*)&Bs[b][k][tx * 4];                 \
                const f32x2 s23 = *(const f32x2*)&Bs[b][k][tx * 4 + 2];             \
                const f32x2 s45 = *(const f32x2*)&Bs[b][k][64 + tx * 4];            \
                const f32x2 s67 = *(const f32x2*)&Bs[b][k][64 + tx * 4 + 2];        \
                const float av[8] = {pa.x, pa.y, pa.z, pa.w, pb.x, pb.y, pb.z, pb.w};\
                const f32x2 sn2[4] = {s01, s23, s45, s67};                          \
                _Pragma("unroll")                                                   \
                for (int m = 0; m < 8; ++m) {                                       \
                    const f32x2 a2 = {av[m], av[m]};                                \
                    _Pragma("unroll")                                               \
                    for (int j = 0; j < 4; ++j)                                     \
                        ca2[m][j] = __builtin_elementwise_fma(a2, sn2[j], ca2[m][j]);\
                }                                                                   \
            }                                                                       \
            if ((((s) + 1) & 31) == 0) {                                            \
                _Pragma("unroll")                                                   \
                for (int m = 0; m < 8; ++m)                                         \
                    _Pragma("unroll")                                               \
                    for (int j = 0; j < 4; ++j) {                                   \
                        ma2[m][j] += ca2[m][j];                                     \
                        ca2[m][j] = (f32x2){0.f, 0.f};                              \
                    }                                                               \
            }                                                                       \
        }

    AISSUE(0, 0);
    __syncthreads();   // buf0 ready

    for (int s2 = 0; s2 < 128; ++s2) {
        const int s = 2 * s2;
        AISSUE(s + 1, 1);
        ACOMP(s, 0);
        __syncthreads();
        if (s + 2 < 256) AISSUE(s + 2, 0);
        ACOMP(s + 1, 1);
        __syncthreads();
    }

    // ---- base MFMA tail (R19/R20-verified): acc reuses ca's dead budget ----
    f32x4 acc[2][8] = {};
    __builtin_amdgcn_s_setprio(1);
    {
        const unsigned short* a0 = Ab + (size_t)(bm0 + w * 32 + r16) * NIN + g * 8;
        const unsigned short* a1 = Ab + (size_t)(bm0 + w * 32 + 16 + r16) * NIN + g * 8;
        #pragma unroll 4
        for (int s = 0; s < 128; ++s) {
            const int k0 = s * 32;
            bf16x8 af0 = *(const bf16x8*)(a0 + k0);
            bf16x8 af1 = *(const bf16x8*)(a1 + k0);
            #pragma unroll
            for (int tc = 0; tc < 8; ++tc) {
                bf16x8 bf = *(const bf16x8*)(SignT + (size_t)(bn0 + tc * 16 + r16) * NIN + k0 + g * 8);
                acc[0][tc] = __builtin_amdgcn_mfma_f32_16x16x32_bf16(af0, bf, acc[0][tc], 0, 0, 0);
                acc[1][tc] = __builtin_amdgcn_mfma_f32_16x16x32_bf16(af1, bf, acc[1][tc], 0, 0, 0);
            }
        }
    }
    __builtin_amdgcn_s_setprio(0);

    // ---- combine + epilogue, two column halves (R18/R19-verified) ----
    __syncthreads();   // As/Bs dead; BoutH alias safe
    #pragma unroll
    for (int hh = 0; hh < 2; ++hh) {
        #pragma unroll
        for (int tr = 0; tr < 2; ++tr)
            #pragma unroll
            for (int tc = 0; tc < 4; ++tc)
                #pragma unroll
                for (int rr = 0; rr < 4; ++rr)
                    BoutH[w * 32 + tr * 16 + g * 4 + rr][tc * 16 + r16] = acc[tr][hh * 4 + tc][rr];
        __syncthreads();
        #pragma unroll
        for (int m = 0; m < 8; ++m) {
            const int row = ty * 8 + m;
            const float4 bv = *(const float4*)&BoutH[row][tx * 4];
            const float bb[4] = {bv.x, bv.y, bv.z, bv.w};
            // half hh uses packed pairs j = hh*2, hh*2+1
            const float mam[4] = {ma2[m][hh * 2 + 0].x, ma2[m][hh * 2 + 0].y,
                                  ma2[m][hh * 2 + 1].x, ma2[m][hh * 2 + 1].y};
            float ph[4];
            #pragma unroll
            for (int n = 0; n < 4; ++n) {
                float r    = mam[n] - bb[n];
                float conc = fabsf(r) / 409.6f;
                float hc   = (r < 0.f) ? (1e-14f / conc) : conc;
                ph[n]      = (-logf(hc)) / 2.302585092994046f;
            }
            *(float4*)(out + (size_t)(bm0 + row) * NOUT + bn0 + hh * 64 + tx * 4) =
                make_float4(ph[0], ph[1], ph[2], ph[3]);
        }
        __syncthreads();
    }
    #undef AISSUE
    #undef ACOMP
}

// Fallback (ws too small): R9's proven all-VALU kernel, on-the-fly terms.
__global__ __launch_bounds__(256, 2) void acid_gemm_fly(const float* __restrict__ X,
                                                        const float* __restrict__ W,
                                                        float* __restrict__ out) {
    __shared__ float2 Asf[32][128 + 2];
    __shared__ float  Bsf[32][64];
    const int tid = threadIdx.x;
    const int tx = tid & 15, ty = tid >> 4;
    const int bm0 = blockIdx.y * 128, bn0 = blockIdx.x * 64;
    float ma[8][4] = {}, mb[8][4] = {}, ca[8][4] = {}, cb[8][4] = {};
    for (int s = 0; s < 128; ++s) {
        const int k0 = s * 32;
        for (int idx = tid; idx < 128 * 32; idx += 256) {
            int m = idx >> 5, k = idx & 31;
            Asf[k][m] = compute_terms(X[(size_t)(bm0 + m) * NIN + k0 + k]);
        }
        for (int idx = tid; idx < 32 * 64; idx += 256) {
            int k = idx >> 6, c = idx & 63;
            Bsf[k][c] = signf_of(W[(size_t)(k0 + k) * NOUT + bn0 + c]);
        }
        __syncthreads();
        #pragma unroll 4
        for (int k = 0; k < 32; ++k) {
            float2 av[8]; float sv[4];
            #pragma unroll
            for (int m = 0; m < 8; ++m) av[m] = Asf[k][ty * 8 + m];
            #pragma unroll
            for (int n = 0; n < 4; ++n) sv[n] = Bsf[k][tx * 4 + n];
            #pragma unroll
            for (int m = 0; m < 8; ++m)
                #pragma unroll
                for (int n = 0; n < 4; ++n) {
                    ca[m][n] = fmaf(av[m].x, sv[n], ca[m][n]);
                    cb[m][n] = fmaf(av[m].y, sv[n], cb[m][n]);
                }
        }
        if (((s + 1) & 15) == 0) {
            #pragma unroll
            for (int m = 0; m < 8; ++m)
                #pragma unroll
                for (int n = 0; n < 4; ++n) {
                    ma[m][n] += ca[m][n]; ca[m][n] = 0.f;
                    mb[m][n] += cb[m][n]; cb[m][n] = 0.f;
                }
        }
        __syncthreads();
    }
    #pragma unroll
    for (int m = 0; m < 8; ++m) {
        int row = bm0 + ty * 8 + m;
        #pragma unroll
        for (int n = 0; n < 4; ++n) {
            int col = bn0 + tx * 4 + n;
            float r = ma[m][n] - mb[m][n];
            float conc = fabsf(r) / 409.6f;
            float hc = (r < 0.f) ? (1e-14f / conc) : conc;
            out[(size_t)row * NOUT + col] = (-logf(hc)) / 2.302585092994046f;
        }
    }
}

extern "C" void kernel_launch(void* const* d_in, const int* in_sizes, int n_in,
                              void* d_out, int out_size, void* d_ws, size_t ws_size,
                              hipStream_t stream) {
    const float* x = (const float*)d_in[0];
    const float* w = (const float*)d_in[1];
    float* out = (float*)d_out;

    const size_t nElem = (size_t)BATCH * NIN;
    // ws layout: AaT f32 | Ab u16 | signT u16 | signF f32  = 12 B/elem (201 MB)
    float*          aaT   = (float*)d_ws;
    unsigned short* ab    = (unsigned short*)((char*)d_ws + nElem * 4);
    unsigned short* signT = (unsigned short*)((char*)d_ws + nElem * 6);
    float*          signF = (float*)((char*)d_ws + nElem * 8);

    if (ws_size >= nElem * 12) {
        precompute_all <<<dim3(64, 128), 256, 0, stream>>>(x, w, aaT, ab, signT, signF);
        acid_base_fused<<<dim3(32, 32), 256, 0, stream>>>(aaT, signF, ab, signT, out);
    } else {
        acid_gemm_fly<<<dim3(NOUT / 64, BATCH / 128), dim3(256), 0, stream>>>(x, w, out);
    }
}